// Round 16
// baseline (339.553 us; speedup 1.0000x reference)
//
#include <hip/hip_runtime.h>
#include <hip/hip_bf16.h>
#include <cstdint>
#include <cstddef>

typedef _Float16 f16;
typedef __attribute__((ext_vector_type(8))) _Float16 f16x8;
typedef __attribute__((ext_vector_type(2))) _Float16 f16x2;
typedef __attribute__((ext_vector_type(4))) float f32x4;
typedef __attribute__((ext_vector_type(16))) float f32x16;

#define LOG2E 1.4426950408889634f
#define QK_SCALE 0.17677669529663687f

__device__ __forceinline__ f32x4 mfma16f(f16x8 a, f16x8 b, f32x4 c) {
  return __builtin_amdgcn_mfma_f32_16x16x32_f16(a, b, c, 0, 0, 0);
}
__device__ __forceinline__ f32x16 mfma32f(f16x8 a, f16x8 b, f32x16 c) {
  return __builtin_amdgcn_mfma_f32_32x32x16_f16(a, b, c, 0, 0, 0);
}
__device__ __forceinline__ float exp2_hw(float x) {
  float r; asm("v_exp_f32 %0, %1" : "=v"(r) : "v"(x)); return r;
}
__device__ __forceinline__ uint32_t cvtpk_f16(float a, float b) {
  uint32_t r; asm("v_cvt_pkrtz_f16_f32 %0, %1, %2" : "=v"(r) : "v"(a), "v"(b)); return r;
}

// rowsum accumulate: acc += p.lo + p.hi  (v_dot2_f32_f16 with ones)
__device__ __forceinline__ float dot2acc(uint32_t u, float acc) {
  union { uint32_t x; f16x2 h; } c; c.x = u;
  f16x2 one2 = {(_Float16)1.0f, (_Float16)1.0f};
  return __builtin_amdgcn_fdot2(c.h, one2, acc, false);
}

// async global->LDS, 16B per lane (dest = uniform base + lane*16)
__device__ __forceinline__ void gl16(const f16* g, f16* l) {
  __builtin_amdgcn_global_load_lds(
      (const __attribute__((address_space(1))) void*)g,
      (__attribute__((address_space(3))) void*)l, 16, 0, 0);
}

// Fragment-packed layout for a [rows][512] fp16 matrix:
// off(m,k) = (((m>>7)*16 + (k>>5))*8 + ((m>>4)&7))*512 + ((k>>3)&3)*128 + (m&15)*8 + (k&7)
__device__ __forceinline__ uint32_t packoff(int m, int k) {
  return (((uint32_t)(m >> 7) * 16u + (uint32_t)(k >> 5)) * 8u + (uint32_t)((m >> 4) & 7)) * 512u
       + (uint32_t)((k >> 3) & 3) * 128u + (uint32_t)(m & 15) * 8u + (uint32_t)(k & 7);
}

// ---------------- prep (+ fused biasF): pack operands (full-line X reads), f32 bias ----------------
__global__ __launch_bounds__(256) void prep_kernel(
    const float* __restrict__ x, const float* __restrict__ wqkv, const float* __restrict__ wproj,
    const float* __restrict__ btab,
    f16* __restrict__ Xp, f16* __restrict__ Wq, f16* __restrict__ Wp,
    float* __restrict__ biasF)
{
  const int XT2 = 16384 * 512 / 32;   // 262144: 2 rows x 16 k per thread
  const int WQT = 1536 * 512 / 16;    // 49152
  const int WPT = 512 * 512 / 16;     // 16384
  int t = blockIdx.x * 256 + threadIdx.x;
  if (t < XT2) {
    uint32_t rp = (uint32_t)t >> 5;
    uint32_t kk = ((uint32_t)t & 31u) << 4;
    uint32_t me = rp << 1;
    const float* s0 = x + (size_t)me * 512 + kk;
    const float* s1 = s0 + 512;
    f32x4 a0 = *(const f32x4*)s0;
    f32x4 a1 = *(const f32x4*)(s0 + 4);
    f32x4 a2 = *(const f32x4*)(s0 + 8);
    f32x4 a3 = *(const f32x4*)(s0 + 12);
    f32x4 b0 = *(const f32x4*)s1;
    f32x4 b1 = *(const f32x4*)(s1 + 4);
    f32x4 b2 = *(const f32x4*)(s1 + 8);
    f32x4 b3 = *(const f32x4*)(s1 + 12);
    uint32_t o = packoff(me, kk);
    f16 r0[8], r1[8], r2[8], r3[8];
    #pragma unroll
    for (int j = 0; j < 4; ++j) {
      r0[j] = (f16)a0[j]; r0[4 + j] = (f16)a1[j];   // (me,   kk..kk+7)
      r1[j] = (f16)b0[j]; r1[4 + j] = (f16)b1[j];   // (me+1, kk..kk+7)
      r2[j] = (f16)a2[j]; r2[4 + j] = (f16)a3[j];   // (me,   kk+8..kk+15)
      r3[j] = (f16)b2[j]; r3[4 + j] = (f16)b3[j];   // (me+1, kk+8..kk+15)
    }
    *(uint4*)(Xp + o)       = *(uint4*)&r0[0];
    *(uint4*)(Xp + o + 8)   = *(uint4*)&r1[0];
    *(uint4*)(Xp + o + 128) = *(uint4*)&r2[0];
    *(uint4*)(Xp + o + 136) = *(uint4*)&r3[0];
  } else if (t < XT2 + WQT) {
    uint32_t o = (uint32_t)(t - XT2) * 16u;
    uint32_t blk = o >> 9, rem = o & 511u;
    uint32_t k23 = rem >> 7, r16 = (rem >> 3) & 15u;
    uint32_t i7 = blk & 7u, k5 = (blk >> 3) & 15u, m7 = blk >> 7;
    uint32_t n = m7 * 128u + i7 * 16u + r16;
    uint32_t k = k5 * 32u + k23 * 8u;
    f16 ov[16];
    #pragma unroll
    for (int j = 0; j < 8; ++j) {
      ov[j] = (f16)wqkv[(size_t)(k + j) * 1536 + n];
      ov[8 + j] = (f16)wqkv[(size_t)(k + j) * 1536 + n + 1];
    }
    *(uint4*)(Wq + o) = *(uint4*)&ov[0];
    *(uint4*)(Wq + o + 8) = *(uint4*)&ov[8];
  } else if (t < XT2 + WQT + WPT) {
    uint32_t o = (uint32_t)(t - XT2 - WQT) * 16u;
    uint32_t blk = o >> 9, rem = o & 511u;
    uint32_t k23 = rem >> 7, r16 = (rem >> 3) & 15u;
    uint32_t i7 = blk & 7u, k5 = (blk >> 3) & 15u, m7 = blk >> 7;
    uint32_t n = m7 * 128u + i7 * 16u + r16;
    uint32_t k = k5 * 32u + k23 * 8u;
    f16 ov[16];
    #pragma unroll
    for (int j = 0; j < 8; ++j) {
      ov[j] = (f16)wproj[(size_t)(k + j) * 512 + n];
      ov[8 + j] = (f16)wproj[(size_t)(k + j) * 512 + n + 1];
    }
    *(uint4*)(Wp + o) = *(uint4*)&ov[0];
    *(uint4*)(Wp + o + 8) = *(uint4*)&ov[8];
  } else {
    int t2 = t - (XT2 + WQT + WPT);
    if (t2 < 16 * 63 * 64) {
      int lane = t2 & 63;
      int sh = t2 >> 6;
      int s = sh % 63, h = sh / 63;
      int lq = lane & 31, hi5 = lane >> 5;
      int base = s * 63 + 31 + lq;
      float o[16];
      #pragma unroll
      for (int r = 0; r < 16; ++r) {
        int kx = (r & 3) + 8 * (r >> 2) + 4 * hi5;
        o[r] = btab[(base - kx) * 16 + h] * LOG2E;
      }
      float* dst = biasF + (size_t)t2 * 16;
      *(uint4*)(dst)      = *(uint4*)&o[0];
      *(uint4*)(dst + 4)  = *(uint4*)&o[4];
      *(uint4*)(dst + 8)  = *(uint4*)&o[8];
      *(uint4*)(dst + 12) = *(uint4*)&o[12];
    }
  }
}

// ---------------- fp16 GEMM: LDS-shared operands, one barrier/chunk, stage-early ----------------
// NB=12: X @ wqkv -> Q(packed)/K/V(pi-permuted) fp16.  NB=4: attnO @ wproj -> fp32 out.
template<int NB>
__global__ __launch_bounds__(256) void gemm_frag(
    const f16* __restrict__ Ap, const f16* __restrict__ Bp,
    const float* __restrict__ bvec,
    f16* __restrict__ Qp, f16* __restrict__ Kp, f16* __restrict__ Vt,
    float* __restrict__ out)
{
  __shared__ f16 sA[3][4096];
  __shared__ f16 sB[3][4096];
  const int bid = blockIdx.x;
  const int xcd = bid & 7, idx = bid >> 3;
  int mb, nb;
  if (NB == 12) { int q = idx / 12; mb = xcd * 16 + q; nb = idx - q * 12; }
  else          { mb = xcd * 16 + (idx >> 2); nb = idx & 3; }
  const int tid = threadIdx.x, lane = tid & 63, wave = tid >> 6;
  const int l15 = lane & 15, l4 = lane >> 4;
  const int wr = wave >> 1, wc = wave & 1;

  const f16* gA = Ap + (uint32_t)mb * 65536u + (uint32_t)wave * 1024u + (uint32_t)lane * 8u;
  const f16* gB = Bp + (uint32_t)nb * 65536u + (uint32_t)wave * 1024u + (uint32_t)lane * 8u;
  const int wl = wave * 1024;

  // prologue: stage chunks 0,1
  gl16(gA,        &sA[0][wl]);
  gl16(gA + 512,  &sA[0][wl + 512]);
  gl16(gB,        &sB[0][wl]);
  gl16(gB + 512,  &sB[0][wl + 512]);
  gl16(gA + 4096, &sA[1][wl]);
  gl16(gA + 4608, &sA[1][wl + 512]);
  gl16(gB + 4096, &sB[1][wl]);
  gl16(gB + 4608, &sB[1][wl + 512]);

  f32x4 acc[4][4];
  #pragma unroll
  for (int i = 0; i < 4; ++i)
    #pragma unroll
    for (int j = 0; j < 4; ++j) acc[i][j] = (f32x4){0.f, 0.f, 0.f, 0.f};

  const uint32_t aoff = (uint32_t)(wr * 4) * 512u + (uint32_t)lane * 8u;
  const uint32_t boff = (uint32_t)(wc * 4) * 512u + (uint32_t)lane * 8u;

  #pragma unroll
  for (int kt = 0; kt < 16; ++kt) {
    asm volatile("s_waitcnt vmcnt(4)" ::: "memory");   // chunk kt landed; kt+1 in flight
    asm volatile("s_barrier" ::: "memory");
    // stage kt+2 FIRST (safety: slab (kt+2)%3's readers drained pre-barrier)
    const int s2 = (kt + 2) % 3;
    gl16(gA + (kt + 2) * 4096,       &sA[s2][wl]);
    gl16(gA + (kt + 2) * 4096 + 512, &sA[s2][wl + 512]);
    gl16(gB + (kt + 2) * 4096,       &sB[s2][wl]);
    gl16(gB + (kt + 2) * 4096 + 512, &sB[s2][wl + 512]);
    __builtin_amdgcn_sched_barrier(0);
    const int s0 = kt % 3;
    f16x8 af[4], bfr[4];
    #pragma unroll
    for (int f = 0; f < 4; ++f) {
      af[f]  = *(const f16x8*)&sA[s0][aoff + f * 512];
      bfr[f] = *(const f16x8*)&sB[s0][boff + f * 512];
    }
    #pragma unroll
    for (int mf = 0; mf < 4; ++mf)
      #pragma unroll
      for (int nf = 0; nf < 4; ++nf)
        acc[mf][nf] = mfma16f(af[mf], bfr[nf], acc[mf][nf]);
  }
  asm volatile("s_waitcnt vmcnt(0)" ::: "memory");     // drain trailing stages

  #pragma unroll
  for (int mf = 0; mf < 4; ++mf) {
    #pragma unroll
    for (int nf = 0; nf < 4; ++nf) {
      int colb = nb * 128 + wc * 64 + nf * 16 + l15;
      float bb = bvec[colb];
      #pragma unroll
      for (int i = 0; i < 4; ++i) {
        int m = mb * 128 + wr * 64 + mf * 16 + l4 * 4 + i;
        float v = acc[mf][nf][i] + bb;
        if (NB == 4) {
          out[(size_t)m * 512 + colb] = v;
        } else {
          int t = colb >> 9, cc = colb & 511;
          int b = m >> 10, n = m & 1023;
          int hh = cc >> 5, d = cc & 31;
          int bh2 = b * 16 + hh;
          if (t == 0) {
            v *= (QK_SCALE * LOG2E);
            // Q pack: [bh][qb(32)][dblk(2)][lane(64)][8]
            uint32_t off = (((uint32_t)bh2 * 32u + (uint32_t)(n >> 5)) * 2u + (uint32_t)(d >> 4)) * 512u
                         + ((uint32_t)((d >> 3) & 1) * 32u + (uint32_t)(n & 31)) * 8u + (uint32_t)(d & 7);
            Qp[off] = (f16)v;
          } else if (t == 1) {
            Kp[((size_t)(bh2 * 2 + (d >> 4)) * 1024 + n) * 16 + (d & 15)] = (f16)v;
          } else {
            // V row pi-permutation (swap rows 4-7 <-> 8-11 within each 16)
            int nl = n & 15;
            int npl = (nl >= 4 && nl < 12) ? (nl ^ 12) : nl;
            int np = (n & ~15) | npl;
            Vt[((size_t)(bh2 * 128 + (np >> 3)) * 32 + d) * 8 + (np & 7)] = (f16)v;
          }
        }
      }
    }
  }
}

// ---------------- fused flash attention: f32 bias direct C-init (zero unpack VALU) ----------------
// grid 1024: xcd = bid&7 owns heads {2*xcd, 2*xcd+1}; 16 b-blocks of one (h,qg) adjacent.
// Bias single-buffered 1 tile ahead (L2-hot); K/V 2-deep; vmcnt(4) discipline preserved.
__global__ __launch_bounds__(256, 4) void attn_kernel(
    const f16* __restrict__ Qp, const f16* __restrict__ Kp, const f16* __restrict__ Vt,
    const float* __restrict__ biasF, f16* __restrict__ Op)
{
  const int bid = blockIdx.x;
  const int xcd = bid & 7, slot = bid >> 3;
  const int h = xcd * 2 + (slot >> 6);
  const int rest = slot & 63;
  const int qg = rest >> 4, b = rest & 15;
  const int bh = b * 16 + h;
  const int tid = threadIdx.x, lane = tid & 63, wave = tid >> 6;
  const int lq = lane & 31, hi5 = lane >> 5;

  const int qb0 = qg * 8 + wave * 2;               // two 32-row q tiles per wave
  const int m0 = b * 1024 + qb0 * 32;

  const uint32_t qbase = ((uint32_t)bh * 32u + (uint32_t)qb0) * 1024u + (uint32_t)lane * 8u;
  const f16x8 q00 = *(const f16x8*)(Qp + qbase);
  const f16x8 q01 = *(const f16x8*)(Qp + qbase + 512);
  const f16x8 q10 = *(const f16x8*)(Qp + qbase + 1024);
  const f16x8 q11 = *(const f16x8*)(Qp + qbase + 1536);

  uint32_t koff = (uint32_t)bh * 32768u + (uint32_t)lq * 16u + (uint32_t)hi5 * 8u;   // K [bh][2][1024][16]
  uint32_t voff = (uint32_t)bh * 32768u + (uint32_t)hi5 * 256u + (uint32_t)lq * 8u;  // V [bh][128][32][8] (pi-permuted)
  // f32 bias: slice stride 1024 floats; qt0 of tile t at slice (qb0+31-t), qt1 = +1 slice
  const float* bpf = biasF + (uint32_t)(h * 63 + qb0 + 31) * 1024u + (uint32_t)lane * 16u;

  union Ub { f32x16 v; f32x4 q[4]; };
  Ub Ue0, Ue1, Uo0, Uo1;

  // prologue order matters for vmcnt: bias(t0) 8, then K/V tiles 0,1 (8)
  Ue0.q[0] = *(const f32x4*)(bpf);
  Ue0.q[1] = *(const f32x4*)(bpf + 4);
  Ue0.q[2] = *(const f32x4*)(bpf + 8);
  Ue0.q[3] = *(const f32x4*)(bpf + 12);
  Ue1.q[0] = *(const f32x4*)(bpf + 1024);
  Ue1.q[1] = *(const f32x4*)(bpf + 1028);
  Ue1.q[2] = *(const f32x4*)(bpf + 1032);
  Ue1.q[3] = *(const f32x4*)(bpf + 1036);
  f16x8 kA0 = *(const f16x8*)(Kp + koff);
  f16x8 kA1 = *(const f16x8*)(Kp + koff + 16384);
  f16x8 vA0 = *(const f16x8*)(Vt + voff);
  f16x8 vA1 = *(const f16x8*)(Vt + voff + 512);
  f16x8 kB0 = *(const f16x8*)(Kp + koff + 512);
  f16x8 kB1 = *(const f16x8*)(Kp + koff + 16384 + 512);
  f16x8 vB0 = *(const f16x8*)(Vt + voff + 1024);
  f16x8 vB1 = *(const f16x8*)(Vt + voff + 1536);

  f32x16 O0, O1;
  #pragma unroll
  for (int i = 0; i < 16; ++i) { O0[i] = 0.f; O1[i] = 0.f; }
  f32x4 racc0 = {0.f, 0.f, 0.f, 0.f}, racc1 = {0.f, 0.f, 0.f, 0.f};

  union Uf { uint32_t u[4]; f16x8 v; };

  auto tile = [&](f16x8& K0, f16x8& K1, f16x8& V0, f16x8& V1,
                  Ub& Uc0, Ub& Uc1, Ub& Un0, Ub& Un1,
                  uint32_t kpre, uint32_t vpre, int bn0, int bn1) {
    asm volatile("s_waitcnt vmcnt(4)" ::: "memory");
    // C-init directly from f32 bias registers (zero unpack)
    f32x16 S0 = mfma32f(K0, q00, Uc0.v);
    S0 = mfma32f(K1, q01, S0);
    f32x16 S1 = mfma32f(K0, q10, Uc1.v);
    S1 = mfma32f(K1, q11, S1);
    // bias(t+1) into the other union set (current set consumed above)
    Un0.q[0] = *(const f32x4*)(bpf + bn0);
    Un0.q[1] = *(const f32x4*)(bpf + bn0 + 4);
    Un0.q[2] = *(const f32x4*)(bpf + bn0 + 8);
    Un0.q[3] = *(const f32x4*)(bpf + bn0 + 12);
    Un1.q[0] = *(const f32x4*)(bpf + bn1);
    Un1.q[1] = *(const f32x4*)(bpf + bn1 + 4);
    Un1.q[2] = *(const f32x4*)(bpf + bn1 + 8);
    Un1.q[3] = *(const f32x4*)(bpf + bn1 + 12);
    // K refill (t+2)
    K0 = *(const f16x8*)(Kp + koff + kpre);
    K1 = *(const f16x8*)(Kp + koff + 16384 + kpre);
    __builtin_amdgcn_sched_barrier(0);
    // q-tile 0: exp2 + pack + dot2 rowsum + PV
    {
      float e0  = exp2_hw(S0[0]),  e1  = exp2_hw(S0[1]),  e2  = exp2_hw(S0[2]),  e3  = exp2_hw(S0[3]);
      float e4  = exp2_hw(S0[4]),  e5  = exp2_hw(S0[5]),  e6  = exp2_hw(S0[6]),  e7  = exp2_hw(S0[7]);
      float e8  = exp2_hw(S0[8]),  e9  = exp2_hw(S0[9]),  e10 = exp2_hw(S0[10]), e11 = exp2_hw(S0[11]);
      float e12 = exp2_hw(S0[12]), e13 = exp2_hw(S0[13]), e14 = exp2_hw(S0[14]), e15 = exp2_hw(S0[15]);
      Uf a1, a2;
      a1.u[0] = cvtpk_f16(e0,  e1);  a1.u[1] = cvtpk_f16(e2,  e3);
      a1.u[2] = cvtpk_f16(e4,  e5);  a1.u[3] = cvtpk_f16(e6,  e7);
      a2.u[0] = cvtpk_f16(e8,  e9);  a2.u[1] = cvtpk_f16(e10, e11);
      a2.u[2] = cvtpk_f16(e12, e13); a2.u[3] = cvtpk_f16(e14, e15);
      racc0[0] = dot2acc(a1.u[0], racc0[0]); racc0[1] = dot2acc(a1.u[1], racc0[1]);
      racc0[2] = dot2acc(a1.u[2], racc0[2]); racc0[3] = dot2acc(a1.u[3], racc0[3]);
      racc0[0] = dot2acc(a2.u[0], racc0[0]); racc0[1] = dot2acc(a2.u[1], racc0[1]);
      racc0[2] = dot2acc(a2.u[2], racc0[2]); racc0[3] = dot2acc(a2.u[3], racc0[3]);
      O0 = mfma32f(a1.v, V0, O0);
      O0 = mfma32f(a2.v, V1, O0);
    }
    // q-tile 1
    {
      float e0  = exp2_hw(S1[0]),  e1  = exp2_hw(S1[1]),  e2  = exp2_hw(S1[2]),  e3  = exp2_hw(S1[3]);
      float e4  = exp2_hw(S1[4]),  e5  = exp2_hw(S1[5]),  e6  = exp2_hw(S1[6]),  e7  = exp2_hw(S1[7]);
      float e8  = exp2_hw(S1[8]),  e9  = exp2_hw(S1[9]),  e10 = exp2_hw(S1[10]), e11 = exp2_hw(S1[11]);
      float e12 = exp2_hw(S1[12]), e13 = exp2_hw(S1[13]), e14 = exp2_hw(S1[14]), e15 = exp2_hw(S1[15]);
      Uf a1, a2;
      a1.u[0] = cvtpk_f16(e0,  e1);  a1.u[1] = cvtpk_f16(e2,  e3);
      a1.u[2] = cvtpk_f16(e4,  e5);  a1.u[3] = cvtpk_f16(e6,  e7);
      a2.u[0] = cvtpk_f16(e8,  e9);  a2.u[1] = cvtpk_f16(e10, e11);
      a2.u[2] = cvtpk_f16(e12, e13); a2.u[3] = cvtpk_f16(e14, e15);
      racc1[0] = dot2acc(a1.u[0], racc1[0]); racc1[1] = dot2acc(a1.u[1], racc1[1]);
      racc1[2] = dot2acc(a1.u[2], racc1[2]); racc1[3] = dot2acc(a1.u[3], racc1[3]);
      racc1[0] = dot2acc(a2.u[0], racc1[0]); racc1[1] = dot2acc(a2.u[1], racc1[1]);
      racc1[2] = dot2acc(a2.u[2], racc1[2]); racc1[3] = dot2acc(a2.u[3], racc1[3]);
      O1 = mfma32f(a1.v, V0, O1);
      O1 = mfma32f(a2.v, V1, O1);
    }
    // V refill (t+2)
    V0 = *(const f16x8*)(Vt + voff + vpre);
    V1 = *(const f16x8*)(Vt + voff + vpre + 512);
    __builtin_amdgcn_sched_barrier(0);
  };

  #pragma unroll 1
  for (int it = 0; it < 16; ++it) {
    // tileA (t): next tile's qt0 slice = bpf-1024, qt1 slice = bpf (same addr as current qt0)
    tile(kA0, kA1, vA0, vA1, Ue0, Ue1, Uo0, Uo1, 1024u, 2048u, -1024, 0);
    // tileB (t+1): next qt0 = bpf-2048, qt1 = bpf-1024
    tile(kB0, kB1, vB0, vB1, Uo0, Uo1, Ue0, Ue1, 1536u, 3072u, -2048, -1024);
    koff += 1024u; voff += 2048u; bpf -= 2048;
  }

  // epilogue: rowsum across halves, reciprocal, shuffle to output rows
  float rs0 = (racc0[0] + racc0[1]) + (racc0[2] + racc0[3]);
  rs0 += __shfl_xor(rs0, 32);
  float inv0 = 1.0f / rs0;
  float rs1 = (racc1[0] + racc1[1]) + (racc1[2] + racc1[3]);
  rs1 += __shfl_xor(rs1, 32);
  float inv1 = 1.0f / rs1;

  const int kcol = h * 32 + lq;
  #pragma unroll
  for (int r = 0; r < 16; ++r) {
    int qrow = (r & 3) + 8 * (r >> 2) + 4 * hi5;
    float t0 = __shfl(inv0, qrow);
    float t1 = __shfl(inv1, qrow);
    Op[packoff(m0 + qrow, kcol)] = (f16)(O0[r] * t0);
    Op[packoff(m0 + 32 + qrow, kcol)] = (f16)(O1[r] * t1);
  }
}

// ---------------- launch ----------------
extern "C" void kernel_launch(void* const* d_in, const int* in_sizes, int n_in,
                              void* d_out, int out_size, void* d_ws, size_t ws_size,
                              hipStream_t stream) {
  const float* x     = (const float*)d_in[0];
  const float* wqkv  = (const float*)d_in[1];
  const float* bqkv  = (const float*)d_in[2];
  const float* wproj = (const float*)d_in[3];
  const float* bproj = (const float*)d_in[4];
  const float* btab  = (const float*)d_in[5];
  // d_in[6] rel_index: unused (index computed analytically)
  float* out = (float*)d_out;

  char* ws = (char*)d_ws;
  size_t off = 0;
  auto walloc = [&](size_t bytes) {
    void* p = ws + off;
    off += (bytes + 255) & ~(size_t)255;
    return p;
  };
  const size_t PAD = 262144;   // pipelines prefetch/stage up to 2 chunks past (or before) the end
  f16* Xp   = (f16*)walloc((size_t)16384 * 512 * 2 + PAD);
  f16* Wq   = (f16*)walloc((size_t)1536 * 512 * 2 + PAD);
  f16* Wp   = (f16*)walloc((size_t)512 * 512 * 2 + PAD);
  f16* Qp   = (f16*)walloc((size_t)16384 * 512 * 2 + PAD);
  f16* Kp   = (f16*)walloc((size_t)16384 * 512 * 2 + PAD);
  f16* Vt   = (f16*)walloc((size_t)16384 * 512 * 2 + PAD);   // biasF negative prefetch lands here (harmless)
  float* biasF = (float*)walloc((size_t)16 * 63 * 64 * 16 * 4 + PAD);
  f16* Op   = (f16*)walloc((size_t)16384 * 512 * 2 + PAD);

  const int prep_total = 16384 * 512 / 32 + 1536 * 512 / 16 + 512 * 512 / 16 + 16 * 63 * 64;
  prep_kernel<<<(prep_total + 255) / 256, 256, 0, stream>>>(
      x, wqkv, wproj, btab, Xp, Wq, Wp, biasF);

  gemm_frag<12><<<1536, 256, 0, stream>>>(
      Xp, Wq, bqkv, Qp, Kp, Vt, nullptr);

  attn_kernel<<<1024, 256, 0, stream>>>(Qp, Kp, Vt, biasF, Op);

  gemm_frag<4><<<512, 256, 0, stream>>>(
      Op, Wp, bproj, nullptr, nullptr, nullptr, out);
}

// Round 17
// 149.689 us; speedup vs baseline: 2.2684x; 2.2684x over previous
//
#include <hip/hip_runtime.h>
#include <hip/hip_bf16.h>
#include <cstdint>
#include <cstddef>

typedef _Float16 f16;
typedef __attribute__((ext_vector_type(8))) _Float16 f16x8;
typedef __attribute__((ext_vector_type(2))) _Float16 f16x2;
typedef __bf16 bf16;
typedef __attribute__((ext_vector_type(4))) float f32x4;
typedef __attribute__((ext_vector_type(16))) float f32x16;

#define LOG2E 1.4426950408889634f
#define QK_SCALE 0.17677669529663687f

__device__ __forceinline__ f32x4 mfma16f(f16x8 a, f16x8 b, f32x4 c) {
  return __builtin_amdgcn_mfma_f32_16x16x32_f16(a, b, c, 0, 0, 0);
}
__device__ __forceinline__ f32x16 mfma32f(f16x8 a, f16x8 b, f32x16 c) {
  return __builtin_amdgcn_mfma_f32_32x32x16_f16(a, b, c, 0, 0, 0);
}
__device__ __forceinline__ float exp2_hw(float x) {
  float r; asm("v_exp_f32 %0, %1" : "=v"(r) : "v"(x)); return r;
}
__device__ __forceinline__ uint32_t cvtpk_f16(float a, float b) {
  uint32_t r; asm("v_cvt_pkrtz_f16_f32 %0, %1, %2" : "=v"(r) : "v"(a), "v"(b)); return r;
}
__device__ __forceinline__ float lo16f(uint32_t u) { return __uint_as_float(u << 16); }
// hi bf16 read as f32 WITHOUT masking: garbage low mantissa, rel err < 2^-7. Free.
__device__ __forceinline__ float hi16raw(uint32_t u) { return __uint_as_float(u); }

// rowsum accumulate: acc += p.lo + p.hi  (v_dot2_f32_f16 with ones)
__device__ __forceinline__ float dot2acc(uint32_t u, float acc) {
  union { uint32_t x; f16x2 h; } c; c.x = u;
  f16x2 one2 = {(_Float16)1.0f, (_Float16)1.0f};
  return __builtin_amdgcn_fdot2(c.h, one2, acc, false);
}

// async global->LDS, 16B per lane (dest = uniform base + lane*16)
__device__ __forceinline__ void gl16(const f16* g, f16* l) {
  __builtin_amdgcn_global_load_lds(
      (const __attribute__((address_space(1))) void*)g,
      (__attribute__((address_space(3))) void*)l, 16, 0, 0);
}

// Fragment-packed layout for a [rows][512] fp16 matrix:
// off(m,k) = (((m>>7)*16 + (k>>5))*8 + ((m>>4)&7))*512 + ((k>>3)&3)*128 + (m&15)*8 + (k&7)
__device__ __forceinline__ uint32_t packoff(int m, int k) {
  return (((uint32_t)(m >> 7) * 16u + (uint32_t)(k >> 5)) * 8u + (uint32_t)((m >> 4) & 7)) * 512u
       + (uint32_t)((k >> 3) & 3) * 128u + (uint32_t)(m & 15) * 8u + (uint32_t)(k & 7);
}

// ---------------- prep (+ fused biasC): pack operands (full-line X reads), bf16 bias ----------------
__global__ __launch_bounds__(256) void prep_kernel(
    const float* __restrict__ x, const float* __restrict__ wqkv, const float* __restrict__ wproj,
    const float* __restrict__ btab,
    f16* __restrict__ Xp, f16* __restrict__ Wq, f16* __restrict__ Wp,
    bf16* __restrict__ biasC)
{
  const int XT2 = 16384 * 512 / 32;   // 262144: 2 rows x 16 k per thread (full 64B line reads)
  const int WQT = 1536 * 512 / 16;    // 49152
  const int WPT = 512 * 512 / 16;     // 16384
  int t = blockIdx.x * 256 + threadIdx.x;
  if (t < XT2) {
    uint32_t rp = (uint32_t)t >> 5;
    uint32_t kk = ((uint32_t)t & 31u) << 4;
    uint32_t me = rp << 1;
    const float* s0 = x + (size_t)me * 512 + kk;
    const float* s1 = s0 + 512;
    f32x4 a0 = *(const f32x4*)s0;
    f32x4 a1 = *(const f32x4*)(s0 + 4);
    f32x4 a2 = *(const f32x4*)(s0 + 8);
    f32x4 a3 = *(const f32x4*)(s0 + 12);
    f32x4 b0 = *(const f32x4*)s1;
    f32x4 b1 = *(const f32x4*)(s1 + 4);
    f32x4 b2 = *(const f32x4*)(s1 + 8);
    f32x4 b3 = *(const f32x4*)(s1 + 12);
    uint32_t o = packoff(me, kk);
    f16 r0[8], r1[8], r2[8], r3[8];
    #pragma unroll
    for (int j = 0; j < 4; ++j) {
      r0[j] = (f16)a0[j]; r0[4 + j] = (f16)a1[j];   // (me,   kk..kk+7)
      r1[j] = (f16)b0[j]; r1[4 + j] = (f16)b1[j];   // (me+1, kk..kk+7)
      r2[j] = (f16)a2[j]; r2[4 + j] = (f16)a3[j];   // (me,   kk+8..kk+15)
      r3[j] = (f16)b2[j]; r3[4 + j] = (f16)b3[j];   // (me+1, kk+8..kk+15)
    }
    *(uint4*)(Xp + o)       = *(uint4*)&r0[0];
    *(uint4*)(Xp + o + 8)   = *(uint4*)&r1[0];
    *(uint4*)(Xp + o + 128) = *(uint4*)&r2[0];
    *(uint4*)(Xp + o + 136) = *(uint4*)&r3[0];
  } else if (t < XT2 + WQT) {
    uint32_t o = (uint32_t)(t - XT2) * 16u;
    uint32_t blk = o >> 9, rem = o & 511u;
    uint32_t k23 = rem >> 7, r16 = (rem >> 3) & 15u;
    uint32_t i7 = blk & 7u, k5 = (blk >> 3) & 15u, m7 = blk >> 7;
    uint32_t n = m7 * 128u + i7 * 16u + r16;
    uint32_t k = k5 * 32u + k23 * 8u;
    f16 ov[16];
    #pragma unroll
    for (int j = 0; j < 8; ++j) {
      ov[j] = (f16)wqkv[(size_t)(k + j) * 1536 + n];
      ov[8 + j] = (f16)wqkv[(size_t)(k + j) * 1536 + n + 1];
    }
    *(uint4*)(Wq + o) = *(uint4*)&ov[0];
    *(uint4*)(Wq + o + 8) = *(uint4*)&ov[8];
  } else if (t < XT2 + WQT + WPT) {
    uint32_t o = (uint32_t)(t - XT2 - WQT) * 16u;
    uint32_t blk = o >> 9, rem = o & 511u;
    uint32_t k23 = rem >> 7, r16 = (rem >> 3) & 15u;
    uint32_t i7 = blk & 7u, k5 = (blk >> 3) & 15u, m7 = blk >> 7;
    uint32_t n = m7 * 128u + i7 * 16u + r16;
    uint32_t k = k5 * 32u + k23 * 8u;
    f16 ov[16];
    #pragma unroll
    for (int j = 0; j < 8; ++j) {
      ov[j] = (f16)wproj[(size_t)(k + j) * 512 + n];
      ov[8 + j] = (f16)wproj[(size_t)(k + j) * 512 + n + 1];
    }
    *(uint4*)(Wp + o) = *(uint4*)&ov[0];
    *(uint4*)(Wp + o + 8) = *(uint4*)&ov[8];
  } else {
    int t2 = t - (XT2 + WQT + WPT);
    if (t2 < 16 * 63 * 64) {
      int lane = t2 & 63;
      int sh = t2 >> 6;
      int s = sh % 63, h = sh / 63;
      int lq = lane & 31, hi5 = lane >> 5;
      int base = s * 63 + 31 + lq;
      bf16 o[16];
      #pragma unroll
      for (int r = 0; r < 16; ++r) {
        int kx = (r & 3) + 8 * (r >> 2) + 4 * hi5;
        o[r] = (bf16)(btab[(base - kx) * 16 + h] * LOG2E);
      }
      *(uint4*)(biasC + (size_t)t2 * 16) = *(uint4*)&o[0];
      *(uint4*)(biasC + (size_t)t2 * 16 + 8) = *(uint4*)&o[8];
    }
  }
}

// ---------------- fp16 GEMM: LDS-shared operands, one barrier/chunk, stage-early ----------------
// NB=12: X @ wqkv -> Q(packed)/K/V(pi-permuted) fp16.  NB=4: attnO @ wproj -> fp32 out.
template<int NB>
__global__ __launch_bounds__(256) void gemm_frag(
    const f16* __restrict__ Ap, const f16* __restrict__ Bp,
    const float* __restrict__ bvec,
    f16* __restrict__ Qp, f16* __restrict__ Kp, f16* __restrict__ Vt,
    float* __restrict__ out)
{
  __shared__ f16 sA[3][4096];
  __shared__ f16 sB[3][4096];
  const int bid = blockIdx.x;
  const int xcd = bid & 7, idx = bid >> 3;
  int mb, nb;
  if (NB == 12) { int q = idx / 12; mb = xcd * 16 + q; nb = idx - q * 12; }
  else          { mb = xcd * 16 + (idx >> 2); nb = idx & 3; }
  const int tid = threadIdx.x, lane = tid & 63, wave = tid >> 6;
  const int l15 = lane & 15, l4 = lane >> 4;
  const int wr = wave >> 1, wc = wave & 1;

  const f16* gA = Ap + (uint32_t)mb * 65536u + (uint32_t)wave * 1024u + (uint32_t)lane * 8u;
  const f16* gB = Bp + (uint32_t)nb * 65536u + (uint32_t)wave * 1024u + (uint32_t)lane * 8u;
  const int wl = wave * 1024;

  // prologue: stage chunks 0,1
  gl16(gA,        &sA[0][wl]);
  gl16(gA + 512,  &sA[0][wl + 512]);
  gl16(gB,        &sB[0][wl]);
  gl16(gB + 512,  &sB[0][wl + 512]);
  gl16(gA + 4096, &sA[1][wl]);
  gl16(gA + 4608, &sA[1][wl + 512]);
  gl16(gB + 4096, &sB[1][wl]);
  gl16(gB + 4608, &sB[1][wl + 512]);

  f32x4 acc[4][4];
  #pragma unroll
  for (int i = 0; i < 4; ++i)
    #pragma unroll
    for (int j = 0; j < 4; ++j) acc[i][j] = (f32x4){0.f, 0.f, 0.f, 0.f};

  const uint32_t aoff = (uint32_t)(wr * 4) * 512u + (uint32_t)lane * 8u;
  const uint32_t boff = (uint32_t)(wc * 4) * 512u + (uint32_t)lane * 8u;

  #pragma unroll
  for (int kt = 0; kt < 16; ++kt) {
    asm volatile("s_waitcnt vmcnt(4)" ::: "memory");   // chunk kt landed; kt+1 in flight
    asm volatile("s_barrier" ::: "memory");
    // stage kt+2 FIRST (safety: slab (kt+2)%3's readers drained pre-barrier)
    const int s2 = (kt + 2) % 3;
    gl16(gA + (kt + 2) * 4096,       &sA[s2][wl]);
    gl16(gA + (kt + 2) * 4096 + 512, &sA[s2][wl + 512]);
    gl16(gB + (kt + 2) * 4096,       &sB[s2][wl]);
    gl16(gB + (kt + 2) * 4096 + 512, &sB[s2][wl + 512]);
    __builtin_amdgcn_sched_barrier(0);
    const int s0 = kt % 3;
    f16x8 af[4], bfr[4];
    #pragma unroll
    for (int f = 0; f < 4; ++f) {
      af[f]  = *(const f16x8*)&sA[s0][aoff + f * 512];
      bfr[f] = *(const f16x8*)&sB[s0][boff + f * 512];
    }
    #pragma unroll
    for (int mf = 0; mf < 4; ++mf)
      #pragma unroll
      for (int nf = 0; nf < 4; ++nf)
        acc[mf][nf] = mfma16f(af[mf], bfr[nf], acc[mf][nf]);
  }
  asm volatile("s_waitcnt vmcnt(0)" ::: "memory");     // drain trailing stages

  #pragma unroll
  for (int mf = 0; mf < 4; ++mf) {
    #pragma unroll
    for (int nf = 0; nf < 4; ++nf) {
      int colb = nb * 128 + wc * 64 + nf * 16 + l15;
      float bb = bvec[colb];
      #pragma unroll
      for (int i = 0; i < 4; ++i) {
        int m = mb * 128 + wr * 64 + mf * 16 + l4 * 4 + i;
        float v = acc[mf][nf][i] + bb;
        if (NB == 4) {
          out[(size_t)m * 512 + colb] = v;
        } else {
          int t = colb >> 9, cc = colb & 511;
          int b = m >> 10, n = m & 1023;
          int hh = cc >> 5, d = cc & 31;
          int bh2 = b * 16 + hh;
          if (t == 0) {
            v *= (QK_SCALE * LOG2E);
            // Q pack: [bh][qb(32)][dblk(2)][lane(64)][8]
            uint32_t off = (((uint32_t)bh2 * 32u + (uint32_t)(n >> 5)) * 2u + (uint32_t)(d >> 4)) * 512u
                         + ((uint32_t)((d >> 3) & 1) * 32u + (uint32_t)(n & 31)) * 8u + (uint32_t)(d & 7);
            Qp[off] = (f16)v;
          } else if (t == 1) {
            Kp[((size_t)(bh2 * 2 + (d >> 4)) * 1024 + n) * 16 + (d & 15)] = (f16)v;
          } else {
            // V row pi-permutation (swap rows 4-7 <-> 8-11 within each 16)
            int nl = n & 15;
            int npl = (nl >= 4 && nl < 12) ? (nl ^ 12) : nl;
            int np = (n & ~15) | npl;
            Vt[((size_t)(bh2 * 128 + (np >> 3)) * 32 + d) * 8 + (np & 7)] = (f16)v;
          }
        }
      }
    }
  }
}

// ---------------- fused flash attention (R13/R15 structure): compressed bf16 bias ----------------
// grid 1024: xcd = bid&7 owns heads {2*xcd, 2*xcd+1}; 16 b-blocks of one (h,qg) adjacent.
__global__ __launch_bounds__(256) void attn_kernel(
    const f16* __restrict__ Qp, const f16* __restrict__ Kp, const f16* __restrict__ Vt,
    const bf16* __restrict__ biasC, f16* __restrict__ Op)
{
  const int bid = blockIdx.x;
  const int xcd = bid & 7, slot = bid >> 3;
  const int h = xcd * 2 + (slot >> 6);
  const int rest = slot & 63;
  const int qg = rest >> 4, b = rest & 15;
  const int bh = b * 16 + h;
  const int tid = threadIdx.x, lane = tid & 63, wave = tid >> 6;
  const int lq = lane & 31, hi5 = lane >> 5;

  const int qb0 = qg * 8 + wave * 2;               // two 32-row q tiles per wave
  const int m0 = b * 1024 + qb0 * 32;

  const uint32_t qbase = ((uint32_t)bh * 32u + (uint32_t)qb0) * 1024u + (uint32_t)lane * 8u;
  const f16x8 q00 = *(const f16x8*)(Qp + qbase);
  const f16x8 q01 = *(const f16x8*)(Qp + qbase + 512);
  const f16x8 q10 = *(const f16x8*)(Qp + qbase + 1024);
  const f16x8 q11 = *(const f16x8*)(Qp + qbase + 1536);

  uint32_t koff = (uint32_t)bh * 32768u + (uint32_t)lq * 16u + (uint32_t)hi5 * 8u;   // K [bh][2][1024][16]
  uint32_t voff = (uint32_t)bh * 32768u + (uint32_t)hi5 * 256u + (uint32_t)lq * 8u;  // V [bh][128][32][8] (pi-permuted)
  const bf16* bp = biasC + ((uint32_t)(h * 63 + qb0 + 31) * 64u + (uint32_t)lane) * 16u;

  // prologue: tile ky=0 (A set) then ky=1 (B set) — 8 loads each
  f16x8 kA0 = *(const f16x8*)(Kp + koff);
  f16x8 kA1 = *(const f16x8*)(Kp + koff + 16384);
  uint4 p0A = *(const uint4*)(bp);
  uint4 p1A = *(const uint4*)(bp + 8);
  uint4 p2A = *(const uint4*)(bp + 1024);
  uint4 p3A = *(const uint4*)(bp + 1032);
  f16x8 vA0 = *(const f16x8*)(Vt + voff);
  f16x8 vA1 = *(const f16x8*)(Vt + voff + 512);
  f16x8 kB0 = *(const f16x8*)(Kp + koff + 512);
  f16x8 kB1 = *(const f16x8*)(Kp + koff + 16384 + 512);
  uint4 p0B = *(const uint4*)(bp - 1024);
  uint4 p1B = *(const uint4*)(bp - 1016);
  uint4 p2B = *(const uint4*)(bp);
  uint4 p3B = *(const uint4*)(bp + 8);
  f16x8 vB0 = *(const f16x8*)(Vt + voff + 1024);
  f16x8 vB1 = *(const f16x8*)(Vt + voff + 1536);

  f32x16 O0, O1;
  #pragma unroll
  for (int i = 0; i < 16; ++i) { O0[i] = 0.f; O1[i] = 0.f; }
  f32x4 racc0 = {0.f, 0.f, 0.f, 0.f}, racc1 = {0.f, 0.f, 0.f, 0.f};

  union Uf { uint32_t u[4]; f16x8 v; };

#define UNPACK16(S, Pa, Pb)                               \
  S[0]  = lo16f(Pa.x); S[1]  = hi16raw(Pa.x);             \
  S[2]  = lo16f(Pa.y); S[3]  = hi16raw(Pa.y);             \
  S[4]  = lo16f(Pa.z); S[5]  = hi16raw(Pa.z);             \
  S[6]  = lo16f(Pa.w); S[7]  = hi16raw(Pa.w);             \
  S[8]  = lo16f(Pb.x); S[9]  = hi16raw(Pb.x);             \
  S[10] = lo16f(Pb.y); S[11] = hi16raw(Pb.y);             \
  S[12] = lo16f(Pb.z); S[13] = hi16raw(Pb.z);             \
  S[14] = lo16f(Pb.w); S[15] = hi16raw(Pb.w);

  auto tile = [&](f16x8& K0, f16x8& K1, f16x8& V0, f16x8& V1,
                  uint4& P0, uint4& P1, uint4& P2, uint4& P3,
                  uint32_t kpre, uint32_t vpre, int bpre) {
    asm volatile("s_waitcnt vmcnt(8)" ::: "memory");
    f32x16 S0, S1;
    UNPACK16(S0, P0, P1)
    UNPACK16(S1, P2, P3)
    S0 = mfma32f(K0, q00, S0);
    S0 = mfma32f(K1, q01, S0);
    S1 = mfma32f(K0, q10, S1);
    S1 = mfma32f(K1, q11, S1);
    // refill K + bias (tile t+2); bias slice walks DOWN
    K0 = *(const f16x8*)(Kp + koff + kpre);
    K1 = *(const f16x8*)(Kp + koff + 16384 + kpre);
    P0 = *(const uint4*)(bp + bpre);
    P1 = *(const uint4*)(bp + bpre + 8);
    P2 = *(const uint4*)(bp + bpre + 1024);
    P3 = *(const uint4*)(bp + bpre + 1032);
    __builtin_amdgcn_sched_barrier(0);
    // q-tile 0: exp2 + pack + dot2 rowsum + PV
    {
      float e0  = exp2_hw(S0[0]),  e1  = exp2_hw(S0[1]),  e2  = exp2_hw(S0[2]),  e3  = exp2_hw(S0[3]);
      float e4  = exp2_hw(S0[4]),  e5  = exp2_hw(S0[5]),  e6  = exp2_hw(S0[6]),  e7  = exp2_hw(S0[7]);
      float e8  = exp2_hw(S0[8]),  e9  = exp2_hw(S0[9]),  e10 = exp2_hw(S0[10]), e11 = exp2_hw(S0[11]);
      float e12 = exp2_hw(S0[12]), e13 = exp2_hw(S0[13]), e14 = exp2_hw(S0[14]), e15 = exp2_hw(S0[15]);
      Uf a1, a2;
      a1.u[0] = cvtpk_f16(e0,  e1);  a1.u[1] = cvtpk_f16(e2,  e3);
      a1.u[2] = cvtpk_f16(e4,  e5);  a1.u[3] = cvtpk_f16(e6,  e7);
      a2.u[0] = cvtpk_f16(e8,  e9);  a2.u[1] = cvtpk_f16(e10, e11);
      a2.u[2] = cvtpk_f16(e12, e13); a2.u[3] = cvtpk_f16(e14, e15);
      racc0[0] = dot2acc(a1.u[0], racc0[0]); racc0[1] = dot2acc(a1.u[1], racc0[1]);
      racc0[2] = dot2acc(a1.u[2], racc0[2]); racc0[3] = dot2acc(a1.u[3], racc0[3]);
      racc0[0] = dot2acc(a2.u[0], racc0[0]); racc0[1] = dot2acc(a2.u[1], racc0[1]);
      racc0[2] = dot2acc(a2.u[2], racc0[2]); racc0[3] = dot2acc(a2.u[3], racc0[3]);
      O0 = mfma32f(a1.v, V0, O0);
      O0 = mfma32f(a2.v, V1, O0);
    }
    // q-tile 1
    {
      float e0  = exp2_hw(S1[0]),  e1  = exp2_hw(S1[1]),  e2  = exp2_hw(S1[2]),  e3  = exp2_hw(S1[3]);
      float e4  = exp2_hw(S1[4]),  e5  = exp2_hw(S1[5]),  e6  = exp2_hw(S1[6]),  e7  = exp2_hw(S1[7]);
      float e8  = exp2_hw(S1[8]),  e9  = exp2_hw(S1[9]),  e10 = exp2_hw(S1[10]), e11 = exp2_hw(S1[11]);
      float e12 = exp2_hw(S1[12]), e13 = exp2_hw(S1[13]), e14 = exp2_hw(S1[14]), e15 = exp2_hw(S1[15]);
      Uf a1, a2;
      a1.u[0] = cvtpk_f16(e0,  e1);  a1.u[1] = cvtpk_f16(e2,  e3);
      a1.u[2] = cvtpk_f16(e4,  e5);  a1.u[3] = cvtpk_f16(e6,  e7);
      a2.u[0] = cvtpk_f16(e8,  e9);  a2.u[1] = cvtpk_f16(e10, e11);
      a2.u[2] = cvtpk_f16(e12, e13); a2.u[3] = cvtpk_f16(e14, e15);
      racc1[0] = dot2acc(a1.u[0], racc1[0]); racc1[1] = dot2acc(a1.u[1], racc1[1]);
      racc1[2] = dot2acc(a1.u[2], racc1[2]); racc1[3] = dot2acc(a1.u[3], racc1[3]);
      racc1[0] = dot2acc(a2.u[0], racc1[0]); racc1[1] = dot2acc(a2.u[1], racc1[1]);
      racc1[2] = dot2acc(a2.u[2], racc1[2]); racc1[3] = dot2acc(a2.u[3], racc1[3]);
      O1 = mfma32f(a1.v, V0, O1);
      O1 = mfma32f(a2.v, V1, O1);
    }
    // refill V (tile t+2)
    V0 = *(const f16x8*)(Vt + voff + vpre);
    V1 = *(const f16x8*)(Vt + voff + vpre + 512);
    __builtin_amdgcn_sched_barrier(0);
  };

  #pragma unroll 1
  for (int it = 0; it < 16; ++it) {
    tile(kA0, kA1, vA0, vA1, p0A, p1A, p2A, p3A, 1024u, 2048u, -2048);
    tile(kB0, kB1, vB0, vB1, p0B, p1B, p2B, p3B, 1536u, 3072u, -3072);
    koff += 1024u; voff += 2048u; bp -= 2048;
  }

  // epilogue: rowsum across halves, reciprocal, shuffle to output rows
  float rs0 = (racc0[0] + racc0[1]) + (racc0[2] + racc0[3]);
  rs0 += __shfl_xor(rs0, 32);
  float inv0 = 1.0f / rs0;
  float rs1 = (racc1[0] + racc1[1]) + (racc1[2] + racc1[3]);
  rs1 += __shfl_xor(rs1, 32);
  float inv1 = 1.0f / rs1;

  const int kcol = h * 32 + lq;
  #pragma unroll
  for (int r = 0; r < 16; ++r) {
    int qrow = (r & 3) + 8 * (r >> 2) + 4 * hi5;
    float t0 = __shfl(inv0, qrow);
    float t1 = __shfl(inv1, qrow);
    Op[packoff(m0 + qrow, kcol)] = (f16)(O0[r] * t0);
    Op[packoff(m0 + 32 + qrow, kcol)] = (f16)(O1[r] * t1);
  }
}

// ---------------- launch ----------------
extern "C" void kernel_launch(void* const* d_in, const int* in_sizes, int n_in,
                              void* d_out, int out_size, void* d_ws, size_t ws_size,
                              hipStream_t stream) {
  const float* x     = (const float*)d_in[0];
  const float* wqkv  = (const float*)d_in[1];
  const float* bqkv  = (const float*)d_in[2];
  const float* wproj = (const float*)d_in[3];
  const float* bproj = (const float*)d_in[4];
  const float* btab  = (const float*)d_in[5];
  // d_in[6] rel_index: unused (index computed analytically)
  float* out = (float*)d_out;

  char* ws = (char*)d_ws;
  size_t off = 0;
  auto walloc = [&](size_t bytes) {
    void* p = ws + off;
    off += (bytes + 255) & ~(size_t)255;
    return p;
  };
  const size_t PAD = 262144;   // pipelines prefetch/stage up to 2 chunks past (or before) the end
  f16* Xp   = (f16*)walloc((size_t)16384 * 512 * 2 + PAD);
  f16* Wq   = (f16*)walloc((size_t)1536 * 512 * 2 + PAD);
  f16* Wp   = (f16*)walloc((size_t)512 * 512 * 2 + PAD);
  f16* Qp   = (f16*)walloc((size_t)16384 * 512 * 2 + PAD);
  f16* Kp   = (f16*)walloc((size_t)16384 * 512 * 2 + PAD);
  f16* Vt   = (f16*)walloc((size_t)16384 * 512 * 2 + PAD);
  bf16* biasC = (bf16*)walloc((size_t)16 * 63 * 64 * 16 * 2 + PAD);
  f16* Op   = (f16*)walloc((size_t)16384 * 512 * 2 + PAD);

  const int prep_total = 16384 * 512 / 32 + 1536 * 512 / 16 + 512 * 512 / 16 + 16 * 63 * 64;
  prep_kernel<<<(prep_total + 255) / 256, 256, 0, stream>>>(
      x, wqkv, wproj, btab, Xp, Wq, Wp, biasC);

  gemm_frag<12><<<1536, 256, 0, stream>>>(
      Xp, Wq, bqkv, Qp, Kp, Vt, nullptr);

  attn_kernel<<<1024, 256, 0, stream>>>(Qp, Kp, Vt, biasC, Op);

  gemm_frag<4><<<512, 256, 0, stream>>>(
      Op, Wp, bproj, nullptr, nullptr, nullptr, out);
}